// Round 1
// baseline (3912.737 us; speedup 1.0000x reference)
//
#include <hip/hip_runtime.h>
#include <hip/hip_bf16.h>

#define EPS 1e-8f
#define B_  16
#define CIN 256
#define COUT 256
#define HW 64
#define CHUNK 8

// ---------------- small precompute kernels ----------------

__global__ __launch_bounds__(256) void s2_reduce_kernel(const float* __restrict__ s,
                                                        float* __restrict__ ssum_out) {
    __shared__ float smem[4];
    int t = threadIdx.x;
    float v = 0.f;
    for (int i = t; i < B_ * CIN; i += 256) {
        float sv = s[i];
        v += sv * sv;
    }
    for (int off = 32; off > 0; off >>= 1) v += __shfl_down(v, off, 64);
    int lane = t & 63, wid = t >> 6;
    if (lane == 0) smem[wid] = v;
    __syncthreads();
    if (t == 0) {
        ssum_out[0] = smem[0] + smem[1] + smem[2] + smem[3];
    }
}

// one block per cout: wsq[co][ci] = sum over 9 taps of w^2 ; wn_scale[co] = rsqrt(mean over 2304)
__global__ __launch_bounds__(256) void wstats_kernel(const float* __restrict__ w,
                                                     float* __restrict__ wsq,
                                                     float* __restrict__ wn_scale) {
    __shared__ float smem[4];
    int co = blockIdx.x;
    int ci = threadIdx.x;
    const float* wp = w + ((size_t)co * CIN + ci) * 9;
    float q = 0.f;
#pragma unroll
    for (int tp = 0; tp < 9; ++tp) {
        float wv = wp[tp];
        q += wv * wv;
    }
    wsq[co * CIN + ci] = q;
    float v = q;
    for (int off = 32; off > 0; off >>= 1) v += __shfl_down(v, off, 64);
    int lane = ci & 63, wid = ci >> 6;
    if (lane == 0) smem[wid] = v;
    __syncthreads();
    if (ci == 0) {
        float total = smem[0] + smem[1] + smem[2] + smem[3];
        wn_scale[co] = rsqrtf(total / 2304.f);
    }
}

// one block per (b,co): coef[b,co] = wn_scale*sn_scale*rsqrt(wn^2*sn^2*sum_ci s^2*wsq + eps)
__global__ __launch_bounds__(256) void coef_kernel(const float* __restrict__ s,
                                                   const float* __restrict__ wsq,
                                                   const float* __restrict__ wn_scale,
                                                   const float* __restrict__ ssum,
                                                   float* __restrict__ coef) {
    __shared__ float smem[4];
    int bid = blockIdx.x;
    int b = bid >> 8;
    int co = bid & 255;
    int ci = threadIdx.x;
    float sv = s[b * CIN + ci];
    float v = sv * sv * wsq[co * CIN + ci];
    for (int off = 32; off > 0; off >>= 1) v += __shfl_down(v, off, 64);
    int lane = ci & 63, wid = ci >> 6;
    if (lane == 0) smem[wid] = v;
    __syncthreads();
    if (ci == 0) {
        float S = smem[0] + smem[1] + smem[2] + smem[3];
        float sn2 = (float)(B_ * CIN) / ssum[0];     // sn_scale^2
        float wn = wn_scale[co];
        float sigma_inv = rsqrtf(wn * wn * sn2 * S + EPS);
        coef[bid] = wn * sqrtf(sn2) * sigma_inv;
    }
}

// ---------------- main conv kernel ----------------
// grid: (16 row-tiles, 64 cout-groups of 4, 16 batch); block: 256 threads
// thread t -> pixel (r = t>>6 in 0..3, c = t&63); computes 4 couts at that pixel.
__global__ __launch_bounds__(256) void conv_kernel(const float* __restrict__ x,
                                                   const float* __restrict__ s,
                                                   const float* __restrict__ w,
                                                   const float* __restrict__ coef,
                                                   float* __restrict__ out) {
    __shared__ float xs[CHUNK][6][66];
    __shared__ float sw[CHUNK][9][4];   // [ci][tap][co_t] -- 16B groups for b128 broadcast

    const int tile = blockIdx.x;   // 0..15
    const int cog  = blockIdx.y;   // 0..63
    const int b    = blockIdx.z;   // 0..15
    const int t = threadIdx.x;
    const int r = t >> 6;
    const int c = t & 63;
    const int r0 = tile * 4;
    const int co0 = cog * 4;

    const float* xb = x + (size_t)b * CIN * HW * HW;
    const float* sb = s + b * CIN;

    float acc0 = 0.f, acc1 = 0.f, acc2 = 0.f, acc3 = 0.f;

    for (int ci0 = 0; ci0 < CIN; ci0 += CHUNK) {
        // stage x tile: CHUNK ci x 6 rows x 66 cols (halo, zero-padded)
        for (int idx = t; idx < CHUNK * 6 * 66; idx += 256) {
            int j = idx / 396;
            int rem = idx - j * 396;
            int row = rem / 66;
            int col = rem - row * 66;
            int gr = r0 - 1 + row;
            int gc = col - 1;
            float v = 0.f;
            if ((unsigned)gr < 64u && (unsigned)gc < 64u)
                v = xb[((ci0 + j) * HW + gr) * HW + gc];
            xs[j][row][col] = v;
        }
        // stage weights * s: sw[j][tap][cc] = w[co0+cc][ci0+j][tap] * s[b][ci0+j]
        for (int idx = t; idx < CHUNK * 9 * 4; idx += 256) {
            int j = idx / 36;
            int rem = idx - j * 36;
            int tap = rem >> 2;
            int cc = rem & 3;
            sw[j][tap][cc] = w[((size_t)(co0 + cc) * CIN + ci0 + j) * 9 + tap] * sb[ci0 + j];
        }
        __syncthreads();

#pragma unroll
        for (int j = 0; j < CHUNK; ++j) {
#pragma unroll
            for (int dr = 0; dr < 3; ++dr) {
                float x0 = xs[j][r + dr][c + 0];
                float x1 = xs[j][r + dr][c + 1];
                float x2 = xs[j][r + dr][c + 2];
                float4 w0 = *(const float4*)&sw[j][dr * 3 + 0][0];
                float4 w1 = *(const float4*)&sw[j][dr * 3 + 1][0];
                float4 w2 = *(const float4*)&sw[j][dr * 3 + 2][0];
                acc0 += x0 * w0.x + x1 * w1.x + x2 * w2.x;
                acc1 += x0 * w0.y + x1 * w1.y + x2 * w2.y;
                acc2 += x0 * w0.z + x1 * w1.z + x2 * w2.z;
                acc3 += x0 * w0.w + x1 * w1.w + x2 * w2.w;
            }
        }
        __syncthreads();
    }

    const float k0 = coef[b * COUT + co0 + 0];
    const float k1 = coef[b * COUT + co0 + 1];
    const float k2 = coef[b * COUT + co0 + 2];
    const float k3 = coef[b * COUT + co0 + 3];
    const int prow = (r0 + r) * HW + c;
    size_t obase = ((size_t)b * COUT + co0) * (HW * HW) + prow;
    out[obase + 0 * (size_t)(HW * HW)] = acc0 * k0;
    out[obase + 1 * (size_t)(HW * HW)] = acc1 * k1;
    out[obase + 2 * (size_t)(HW * HW)] = acc2 * k2;
    out[obase + 3 * (size_t)(HW * HW)] = acc3 * k3;
}

extern "C" void kernel_launch(void* const* d_in, const int* in_sizes, int n_in,
                              void* d_out, int out_size, void* d_ws, size_t ws_size,
                              hipStream_t stream) {
    const float* x = (const float*)d_in[0];   // [16,256,64,64]
    const float* s = (const float*)d_in[1];   // [16,256]
    const float* w = (const float*)d_in[2];   // [256,256,3,3]
    float* out = (float*)d_out;               // [16,256,64,64]

    float* ws = (float*)d_ws;
    float* ssum     = ws;                 // 1 float
    float* wn_scale = ws + 16;            // 256 floats
    float* wsq      = ws + 512;           // 65536 floats
    float* coef     = ws + 512 + 65536;   // 4096 floats

    s2_reduce_kernel<<<1, 256, 0, stream>>>(s, ssum);
    wstats_kernel<<<COUT, 256, 0, stream>>>(w, wsq, wn_scale);
    coef_kernel<<<B_ * COUT, 256, 0, stream>>>(s, wsq, wn_scale, ssum, coef);

    dim3 grid(16, COUT / 4, B_);
    conv_kernel<<<grid, 256, 0, stream>>>(x, s, w, coef, out);
}

// Round 2
// 349.821 us; speedup vs baseline: 11.1850x; 11.1850x over previous
//
#include <hip/hip_runtime.h>
#include <hip/hip_bf16.h>

#define EPS 1e-8f
#define B_  16
#define CIN 256
#define COUT 256
#define HW 64
#define KC 32          // ci per chunk (= MFMA K)
#define CIP 40         // padded ci stride in LDS (40*2B=80B breaks bank alignment)

typedef __bf16 bf16x8 __attribute__((ext_vector_type(8)));
typedef float  f32x4  __attribute__((ext_vector_type(4)));

// ---------------- small precompute kernels ----------------

__global__ __launch_bounds__(256) void s2_reduce_kernel(const float* __restrict__ s,
                                                        float* __restrict__ ssum_out) {
    __shared__ float smem[4];
    int t = threadIdx.x;
    float v = 0.f;
    for (int i = t; i < B_ * CIN; i += 256) {
        float sv = s[i];
        v += sv * sv;
    }
    for (int off = 32; off > 0; off >>= 1) v += __shfl_down(v, off, 64);
    int lane = t & 63, wid = t >> 6;
    if (lane == 0) smem[wid] = v;
    __syncthreads();
    if (t == 0) ssum_out[0] = smem[0] + smem[1] + smem[2] + smem[3];
}

__global__ __launch_bounds__(256) void wstats_kernel(const float* __restrict__ w,
                                                     float* __restrict__ wsq,
                                                     float* __restrict__ wn_scale) {
    __shared__ float smem[4];
    int co = blockIdx.x;
    int ci = threadIdx.x;
    const float* wp = w + ((size_t)co * CIN + ci) * 9;
    float q = 0.f;
#pragma unroll
    for (int tp = 0; tp < 9; ++tp) { float wv = wp[tp]; q += wv * wv; }
    wsq[co * CIN + ci] = q;
    float v = q;
    for (int off = 32; off > 0; off >>= 1) v += __shfl_down(v, off, 64);
    int lane = ci & 63, wid = ci >> 6;
    if (lane == 0) smem[wid] = v;
    __syncthreads();
    if (ci == 0) {
        float total = smem[0] + smem[1] + smem[2] + smem[3];
        wn_scale[co] = rsqrtf(total / 2304.f);
    }
}

__global__ __launch_bounds__(256) void coef_kernel(const float* __restrict__ s,
                                                   const float* __restrict__ wsq,
                                                   const float* __restrict__ wn_scale,
                                                   const float* __restrict__ ssum,
                                                   float* __restrict__ coef) {
    __shared__ float smem[4];
    int bid = blockIdx.x;
    int b = bid >> 8;
    int co = bid & 255;
    int ci = threadIdx.x;
    float sv = s[b * CIN + ci];
    float v = sv * sv * wsq[co * CIN + ci];
    for (int off = 32; off > 0; off >>= 1) v += __shfl_down(v, off, 64);
    int lane = ci & 63, wid = ci >> 6;
    if (lane == 0) smem[wid] = v;
    __syncthreads();
    if (ci == 0) {
        float S = smem[0] + smem[1] + smem[2] + smem[3];
        float sn2 = (float)(B_ * CIN) / ssum[0];     // sn_scale^2
        float wn = wn_scale[co];
        float sigma_inv = rsqrtf(wn * wn * sn2 * S + EPS);
        coef[bid] = wn * sqrtf(sn2) * sigma_inv;     // folds wn*sn*sigma_inv
    }
}

// wfull[b][tap][co][ci] = bf16( w[co][ci][tap] * s[b][ci] * coef[b][co] )
__global__ __launch_bounds__(256) void modweight_kernel(const float* __restrict__ w,
                                                        const float* __restrict__ s,
                                                        const float* __restrict__ coef,
                                                        __bf16* __restrict__ wfull) {
    int ci = threadIdx.x;
    int co = blockIdx.x;
    int b  = blockIdx.y;
    float sc = s[b * CIN + ci] * coef[b * COUT + co];
    const float* wp = w + ((size_t)co * CIN + ci) * 9;
#pragma unroll
    for (int tap = 0; tap < 9; ++tap) {
        wfull[(((size_t)b * 9 + tap) * COUT + co) * CIN + ci] = (__bf16)(wp[tap] * sc);
    }
}

// ---------------- MFMA implicit-GEMM conv ----------------
// grid: (32 row-pair tiles, 2 co-halves, 16 batch); block 256 = 4 waves.
// wave w: wy=w>>1 picks 64-co half, wx=w&1 picks image row within pair.
// Each wave: 4x4 tiles of mfma_f32_16x16x32_bf16 -> 64 co x 64 px.
__global__ __launch_bounds__(256) void conv_mfma(const float* __restrict__ x,
                                                 const __bf16* __restrict__ wfull,
                                                 float* __restrict__ out) {
    __shared__ __bf16 xs[4 * 66 * CIP];   // 21120 B: [row 0..3][col 0..65][ci 0..31 pad 40]

    const int pxt = blockIdx.x;           // 0..31: rows r0=2*pxt, r0+1
    const int coB = blockIdx.y * 128;
    const int b   = blockIdx.z;
    const int t = threadIdx.x;
    const int wv = t >> 6, lane = t & 63;
    const int wy = wv >> 1, wx = wv & 1;
    const int m16 = lane & 15, q = lane >> 4;
    const int r0 = pxt * 2;

    const float* xb = x + (size_t)b * CIN * (HW * HW);
    f32x4 acc[4][4] = {};

    for (int ci0 = 0; ci0 < CIN; ci0 += KC) {
        // stage x halo tile: 4 rows x 66 cols x 32 ci (bf16, ci-contiguous)
        for (int idx = t; idx < 4 * 66 * KC; idx += 256) {
            int col = idx % 66;
            int tmp = idx / 66;
            int row = tmp & 3;
            int ci  = tmp >> 2;
            int gr = r0 - 1 + row, gc = col - 1;
            float v = 0.f;
            if ((unsigned)gr < 64u && (unsigned)gc < 64u)
                v = xb[(ci0 + ci) * (HW * HW) + gr * HW + gc];
            xs[(row * 66 + col) * CIP + ci] = (__bf16)v;
        }
        __syncthreads();

        const __bf16* wbase = wfull + (((size_t)b * 9) * COUT + coB + wy * 64 + m16) * CIN
                              + ci0 + q * 8;
#pragma unroll
        for (int tap = 0; tap < 9; ++tap) {
            const int dr = tap / 3, dc = tap % 3;
            bf16x8 bf[4];
            const int browbase = ((wx + dr) * 66 + (m16 + dc)) * CIP + q * 8;
#pragma unroll
            for (int j = 0; j < 4; ++j)
                bf[j] = *(const bf16x8*)&xs[browbase + j * 16 * CIP];
            bf16x8 af[4];
#pragma unroll
            for (int i = 0; i < 4; ++i)
                af[i] = *(const bf16x8*)(wbase + ((size_t)tap * COUT + i * 16) * CIN);
#pragma unroll
            for (int i = 0; i < 4; ++i)
#pragma unroll
                for (int j = 0; j < 4; ++j)
                    acc[i][j] = __builtin_amdgcn_mfma_f32_16x16x32_bf16(af[i], bf[j], acc[i][j], 0, 0, 0);
        }
        __syncthreads();
    }

    // epilogue: D col = lane&15 (pixel), row = q*4+reg (co)
    const int orow = r0 + wx;
#pragma unroll
    for (int i = 0; i < 4; ++i) {
        const int cobase = coB + wy * 64 + i * 16 + q * 4;
#pragma unroll
        for (int reg = 0; reg < 4; ++reg) {
            float* op = out + ((size_t)b * COUT + (cobase + reg)) * (HW * HW) + orow * HW;
#pragma unroll
            for (int j = 0; j < 4; ++j)
                op[j * 16 + m16] = acc[i][j][reg];
        }
    }
}

extern "C" void kernel_launch(void* const* d_in, const int* in_sizes, int n_in,
                              void* d_out, int out_size, void* d_ws, size_t ws_size,
                              hipStream_t stream) {
    const float* x = (const float*)d_in[0];   // [16,256,64,64]
    const float* s = (const float*)d_in[1];   // [16,256]
    const float* w = (const float*)d_in[2];   // [256,256,3,3]
    float* out = (float*)d_out;               // [16,256,64,64]

    float* ws = (float*)d_ws;
    float* ssum     = ws;                  // 1
    float* wn_scale = ws + 16;             // 256
    float* wsq      = ws + 512;            // 65536
    float* coef     = ws + 66048;          // 4096
    __bf16* wfull   = (__bf16*)(ws + 70656); // 16*9*256*256 bf16 = 18.9 MB

    s2_reduce_kernel<<<1, 256, 0, stream>>>(s, ssum);
    wstats_kernel<<<COUT, 256, 0, stream>>>(w, wsq, wn_scale);
    coef_kernel<<<B_ * COUT, 256, 0, stream>>>(s, wsq, wn_scale, ssum, coef);
    modweight_kernel<<<dim3(COUT, B_), 256, 0, stream>>>(w, s, coef, wfull);

    dim3 grid(32, 2, B_);
    conv_mfma<<<grid, 256, 0, stream>>>(x, wfull, out);
}

// Round 3
// 313.765 us; speedup vs baseline: 12.4703x; 1.1149x over previous
//
#include <hip/hip_runtime.h>
#include <hip/hip_bf16.h>

#define EPS 1e-8f
#define B_  16
#define CIN 256
#define COUT 256
#define HW 64

typedef __bf16 bf16x8 __attribute__((ext_vector_type(8)));
typedef float  f32x4  __attribute__((ext_vector_type(4)));

__device__ __forceinline__ void async16(void* lds, const void* g) {
    __builtin_amdgcn_global_load_lds(
        (const __attribute__((address_space(1))) unsigned int*)g,
        (__attribute__((address_space(3))) unsigned int*)lds,
        16, 0, 0);
}

// ---------------- small precompute kernels ----------------

__global__ __launch_bounds__(256) void s2_reduce_kernel(const float* __restrict__ s,
                                                        float* __restrict__ ssum_out) {
    __shared__ float smem[4];
    int t = threadIdx.x;
    float v = 0.f;
    for (int i = t; i < B_ * CIN; i += 256) { float sv = s[i]; v += sv * sv; }
    for (int off = 32; off > 0; off >>= 1) v += __shfl_down(v, off, 64);
    int lane = t & 63, wid = t >> 6;
    if (lane == 0) smem[wid] = v;
    __syncthreads();
    if (t == 0) ssum_out[0] = smem[0] + smem[1] + smem[2] + smem[3];
}

__global__ __launch_bounds__(256) void wstats_kernel(const float* __restrict__ w,
                                                     float* __restrict__ wsq,
                                                     float* __restrict__ wn_scale) {
    __shared__ float smem[4];
    int co = blockIdx.x;
    int ci = threadIdx.x;
    const float* wp = w + ((size_t)co * CIN + ci) * 9;
    float q = 0.f;
#pragma unroll
    for (int tp = 0; tp < 9; ++tp) { float wv = wp[tp]; q += wv * wv; }
    wsq[co * CIN + ci] = q;
    float v = q;
    for (int off = 32; off > 0; off >>= 1) v += __shfl_down(v, off, 64);
    int lane = ci & 63, wid = ci >> 6;
    if (lane == 0) smem[wid] = v;
    __syncthreads();
    if (ci == 0) {
        float total = smem[0] + smem[1] + smem[2] + smem[3];
        wn_scale[co] = rsqrtf(total / 2304.f);
    }
}

__global__ __launch_bounds__(256) void coef_kernel(const float* __restrict__ s,
                                                   const float* __restrict__ wsq,
                                                   const float* __restrict__ wn_scale,
                                                   const float* __restrict__ ssum,
                                                   float* __restrict__ coef) {
    __shared__ float smem[4];
    int bid = blockIdx.x;
    int b = bid >> 8;
    int co = bid & 255;
    int ci = threadIdx.x;
    float sv = s[b * CIN + ci];
    float v = sv * sv * wsq[co * CIN + ci];
    for (int off = 32; off > 0; off >>= 1) v += __shfl_down(v, off, 64);
    int lane = ci & 63, wid = ci >> 6;
    if (lane == 0) smem[wid] = v;
    __syncthreads();
    if (ci == 0) {
        float S = smem[0] + smem[1] + smem[2] + smem[3];
        float sn2 = (float)(B_ * CIN) / ssum[0];
        float wn = wn_scale[co];
        float sigma_inv = rsqrtf(wn * wn * sn2 * S + EPS);
        coef[bid] = wn * sqrtf(sn2) * sigma_inv;
    }
}

// wfull[b][tap][co][ci] = bf16( w[co][ci][tap] * s[b][ci] * coef[b][co] )
__global__ __launch_bounds__(256) void modweight_kernel(const float* __restrict__ w,
                                                        const float* __restrict__ s,
                                                        const float* __restrict__ coef,
                                                        __bf16* __restrict__ wfull) {
    int ci = threadIdx.x;
    int co = blockIdx.x;
    int b  = blockIdx.y;
    float sc = s[b * CIN + ci] * coef[b * COUT + co];
    const float* wp = w + ((size_t)co * CIN + ci) * 9;
#pragma unroll
    for (int tap = 0; tap < 9; ++tap) {
        wfull[(((size_t)b * 9 + tap) * COUT + co) * CIN + ci] = (__bf16)(wp[tap] * sc);
    }
}

// x [b][ci][r][c] fp32 -> xbf [b][r][col 0..65][ci] bf16, cols 0/65 zero.
// grid (32 row-pairs, 16 b), block 256: t>>7 = row in pair, ci2 = (t&127)*2.
__global__ __launch_bounds__(256) void xbf_kernel(const float* __restrict__ x,
                                                  __bf16* __restrict__ xbf) {
    const int b  = blockIdx.y;
    const int t  = threadIdx.x;
    const int row = blockIdx.x * 2 + (t >> 7);
    const int ci2 = (t & 127) * 2;
    const float* xr0 = x + (((size_t)b * CIN + ci2) * HW + row) * HW;
    const float* xr1 = xr0 + HW * HW;
    __bf16* orow = xbf + (((size_t)b * HW + row) * 66) * CIN;
    // zero borders (col 0 and 65)
    *(ushort2*)&orow[0 * CIN + ci2]  = make_ushort2(0, 0);
    *(ushort2*)&orow[65 * CIN + ci2] = make_ushort2(0, 0);
#pragma unroll
    for (int c4 = 0; c4 < 16; ++c4) {
        float4 a = ((const float4*)xr0)[c4];
        float4 c = ((const float4*)xr1)[c4];
        __bf16* op = orow + (c4 * 4 + 1) * CIN + ci2;
        __bf16 pr[8] = {(__bf16)a.x, (__bf16)c.x, (__bf16)a.y, (__bf16)c.y,
                        (__bf16)a.z, (__bf16)c.z, (__bf16)a.w, (__bf16)c.w};
#pragma unroll
        for (int k = 0; k < 4; ++k)
            *(ushort*)&op[k * CIN] = *(ushort*)&pr[2 * k],
            *(ushort*)&op[k * CIN + 1] = *(ushort*)&pr[2 * k + 1];
    }
}

// ---------------- MFMA implicit-GEMM conv, v2 ----------------
// grid (32 pxt, 16 b), block 512 = 8 waves: wy = wv>>1 (co quarter), wx = wv&1 (row).
// Each wave: 64 co x 64 px, 4x4 tiles of mfma_f32_16x16x32_bf16.
// LDS x tile: [q 0..3][row 0..3][col 0..65] 16B blocks (8 ci each) + 32 pad slots.
__global__ __launch_bounds__(512, 4) void conv_mfma2(const __bf16* __restrict__ xbf,
                                                     const __bf16* __restrict__ zrow,
                                                     const __bf16* __restrict__ wfull,
                                                     float* __restrict__ out) {
    __shared__ __attribute__((aligned(16))) __bf16 xs[1088 * 8];  // 17408 B

    const int pxt = blockIdx.x;
    const int b   = blockIdx.y;
    const int t = threadIdx.x;
    const int wv = t >> 6, lane = t & 63;
    const int wy = wv >> 1, wx = wv & 1;
    const int m16 = lane & 15, q = lane >> 4;
    const int r0 = pxt * 2;

    // precompute staging sources: 17 wave-instrs over 1088 slots
    const __bf16* gsrc[3];
    unsigned ldsoff[3];
    int nst = 0;
#pragma unroll
    for (int i = 0; i < 3; ++i) {
        int instr = wv + 8 * i;
        if (instr < 17) {
            int slot = instr * 64 + lane;       // 0..1087
            const __bf16* g;
            if (slot >= 1056) {
                g = zrow;                        // pad slots (never read)
            } else {
                int qq  = slot / 264;
                int rem = slot - qq * 264;
                int row = rem / 66;
                int col = rem - row * 66;
                int gr = r0 - 1 + row;
                if ((unsigned)gr < 64u)
                    g = xbf + (((size_t)b * HW + gr) * 66 + col) * CIN + qq * 8;
                else
                    g = zrow + col * CIN + qq * 8;
            }
            gsrc[nst] = g;
            ldsoff[nst] = (unsigned)slot * 16;
            ++nst;
        }
    }

    f32x4 acc[4][4] = {};
    const __bf16* abase = wfull + (((size_t)b * 9 * COUT) + wy * 64 + m16) * CIN + q * 8;

    for (int ci0 = 0; ci0 < CIN; ci0 += 32) {
        for (int i = 0; i < nst; ++i)
            async16((char*)xs + ldsoff[i], gsrc[i] + ci0);
        __syncthreads();

        const __bf16* wb = abase + ci0;
#pragma unroll
        for (int tap = 0; tap < 9; ++tap) {
            const int dr = tap / 3, dc = tap % 3;
            bf16x8 af[4];
#pragma unroll
            for (int i = 0; i < 4; ++i)
                af[i] = *(const bf16x8*)(wb + (size_t)tap * (COUT * CIN) + i * 16 * CIN);
            bf16x8 bfr[4];
            const int rb = (((q * 4) + (wx + dr)) * 66 + (m16 + dc)) * 8;
#pragma unroll
            for (int j = 0; j < 4; ++j)
                bfr[j] = *(const bf16x8*)&xs[rb + j * 16 * 8];
#pragma unroll
            for (int i = 0; i < 4; ++i)
#pragma unroll
                for (int j = 0; j < 4; ++j)
                    acc[i][j] = __builtin_amdgcn_mfma_f32_16x16x32_bf16(af[i], bfr[j], acc[i][j], 0, 0, 0);
        }
        __syncthreads();
    }

    const int orow = r0 + wx;
#pragma unroll
    for (int i = 0; i < 4; ++i) {
        const int cobase = wy * 64 + i * 16 + q * 4;
#pragma unroll
        for (int reg = 0; reg < 4; ++reg) {
            float* op = out + ((size_t)b * COUT + (cobase + reg)) * (HW * HW) + orow * HW;
#pragma unroll
            for (int j = 0; j < 4; ++j)
                op[j * 16 + m16] = acc[i][j][reg];
        }
    }
}

// ---------------- fallback (R2, proven) ----------------
#define KC 32
#define CIP 40
__global__ __launch_bounds__(256) void conv_mfma(const float* __restrict__ x,
                                                 const __bf16* __restrict__ wfull,
                                                 float* __restrict__ out) {
    __shared__ __bf16 xs[4 * 66 * CIP];
    const int pxt = blockIdx.x;
    const int coB = blockIdx.y * 128;
    const int b   = blockIdx.z;
    const int t = threadIdx.x;
    const int wv = t >> 6, lane = t & 63;
    const int wy = wv >> 1, wx = wv & 1;
    const int m16 = lane & 15, q = lane >> 4;
    const int r0 = pxt * 2;
    const float* xb = x + (size_t)b * CIN * (HW * HW);
    f32x4 acc[4][4] = {};
    for (int ci0 = 0; ci0 < CIN; ci0 += KC) {
        for (int idx = t; idx < 4 * 66 * KC; idx += 256) {
            int col = idx % 66;
            int tmp = idx / 66;
            int row = tmp & 3;
            int ci  = tmp >> 2;
            int gr = r0 - 1 + row, gc = col - 1;
            float v = 0.f;
            if ((unsigned)gr < 64u && (unsigned)gc < 64u)
                v = xb[(ci0 + ci) * (HW * HW) + gr * HW + gc];
            xs[(row * 66 + col) * CIP + ci] = (__bf16)v;
        }
        __syncthreads();
        const __bf16* wbase = wfull + (((size_t)b * 9) * COUT + coB + wy * 64 + m16) * CIN + ci0 + q * 8;
#pragma unroll
        for (int tap = 0; tap < 9; ++tap) {
            const int dr = tap / 3, dc = tap % 3;
            bf16x8 bfr[4];
            const int browbase = ((wx + dr) * 66 + (m16 + dc)) * CIP + q * 8;
#pragma unroll
            for (int j = 0; j < 4; ++j)
                bfr[j] = *(const bf16x8*)&xs[browbase + j * 16 * CIP];
            bf16x8 af[4];
#pragma unroll
            for (int i = 0; i < 4; ++i)
                af[i] = *(const bf16x8*)(wbase + ((size_t)tap * COUT + i * 16) * CIN);
#pragma unroll
            for (int i = 0; i < 4; ++i)
#pragma unroll
                for (int j = 0; j < 4; ++j)
                    acc[i][j] = __builtin_amdgcn_mfma_f32_16x16x32_bf16(af[i], bfr[j], acc[i][j], 0, 0, 0);
        }
        __syncthreads();
    }
    const int orow = r0 + wx;
#pragma unroll
    for (int i = 0; i < 4; ++i) {
        const int cobase = coB + wy * 64 + i * 16 + q * 4;
#pragma unroll
        for (int reg = 0; reg < 4; ++reg) {
            float* op = out + ((size_t)b * COUT + (cobase + reg)) * (HW * HW) + orow * HW;
#pragma unroll
            for (int j = 0; j < 4; ++j)
                op[j * 16 + m16] = acc[i][j][reg];
        }
    }
}

extern "C" void kernel_launch(void* const* d_in, const int* in_sizes, int n_in,
                              void* d_out, int out_size, void* d_ws, size_t ws_size,
                              hipStream_t stream) {
    const float* x = (const float*)d_in[0];
    const float* s = (const float*)d_in[1];
    const float* w = (const float*)d_in[2];
    float* out = (float*)d_out;

    float* ws = (float*)d_ws;
    float*  ssum     = ws;
    float*  wn_scale = ws + 16;
    float*  wsq      = ws + 512;
    float*  coef     = ws + 66048;
    __bf16* wfull    = (__bf16*)(ws + 70656);            // 18,874,368 B
    __bf16* zrow     = (__bf16*)(ws + 4789248);          // 33,792 B
    __bf16* xbf      = (__bf16*)(ws + 4797696);          // 34,603,008 B
    const size_t need = 53793792;

    s2_reduce_kernel<<<1, 256, 0, stream>>>(s, ssum);
    wstats_kernel<<<COUT, 256, 0, stream>>>(w, wsq, wn_scale);
    coef_kernel<<<B_ * COUT, 256, 0, stream>>>(s, wsq, wn_scale, ssum, coef);
    modweight_kernel<<<dim3(COUT, B_), 256, 0, stream>>>(w, s, coef, wfull);

    if (ws_size >= need) {
        hipMemsetAsync(zrow, 0, 33792, stream);
        xbf_kernel<<<dim3(32, B_), 256, 0, stream>>>(x, xbf);
        conv_mfma2<<<dim3(32, B_), 512, 0, stream>>>(xbf, zrow, wfull, out);
    } else {
        conv_mfma<<<dim3(32, 2, B_), 256, 0, stream>>>(x, wfull, out);
    }
}

// Round 4
// 292.213 us; speedup vs baseline: 13.3900x; 1.0738x over previous
//
#include <hip/hip_runtime.h>
#include <hip/hip_bf16.h>

#define EPS 1e-8f
#define B_  16
#define CIN 256
#define COUT 256
#define HW 64

typedef __bf16 bf16x8 __attribute__((ext_vector_type(8)));
typedef float  f32x4  __attribute__((ext_vector_type(4)));

__device__ __forceinline__ void async16(void* lds, const void* g) {
    __builtin_amdgcn_global_load_lds(
        (const __attribute__((address_space(1))) unsigned int*)g,
        (__attribute__((address_space(3))) unsigned int*)lds,
        16, 0, 0);
}

// ---------------- fused stats: blocks 0..255 = per-co wsq/wn_scale; block 256 = ssum ----------------
__global__ __launch_bounds__(256) void stats_kernel(const float* __restrict__ w,
                                                    const float* __restrict__ s,
                                                    float* __restrict__ wsq,
                                                    float* __restrict__ wn_scale,
                                                    float* __restrict__ ssum_out) {
    __shared__ float smem[4];
    const int t = threadIdx.x;
    const int lane = t & 63, wid = t >> 6;
    if (blockIdx.x == 256) {
        float v = 0.f;
        for (int i = t; i < B_ * CIN; i += 256) { float sv = s[i]; v += sv * sv; }
        for (int off = 32; off > 0; off >>= 1) v += __shfl_down(v, off, 64);
        if (lane == 0) smem[wid] = v;
        __syncthreads();
        if (t == 0) ssum_out[0] = smem[0] + smem[1] + smem[2] + smem[3];
        return;
    }
    const int co = blockIdx.x;
    const float* wp = w + ((size_t)co * CIN + t) * 9;
    float q = 0.f;
#pragma unroll
    for (int tp = 0; tp < 9; ++tp) { float wv = wp[tp]; q += wv * wv; }
    wsq[co * CIN + t] = q;
    float v = q;
    for (int off = 32; off > 0; off >>= 1) v += __shfl_down(v, off, 64);
    if (lane == 0) smem[wid] = v;
    __syncthreads();
    if (t == 0) wn_scale[co] = rsqrtf((smem[0] + smem[1] + smem[2] + smem[3]) / 2304.f);
}

// ---------------- fused coef + modulated-weight materialization ----------------
// grid (256 co, 16 b), 256 threads = ci
__global__ __launch_bounds__(256) void wmod_kernel(const float* __restrict__ w,
                                                   const float* __restrict__ s,
                                                   const float* __restrict__ wsq,
                                                   const float* __restrict__ wn_scale,
                                                   const float* __restrict__ ssum,
                                                   __bf16* __restrict__ wfull) {
    __shared__ float smem[4];
    __shared__ float coef_s;
    const int co = blockIdx.x;
    const int b  = blockIdx.y;
    const int ci = threadIdx.x;
    const int lane = ci & 63, wid = ci >> 6;
    const float sv = s[b * CIN + ci];
    float v = sv * sv * wsq[co * CIN + ci];
    for (int off = 32; off > 0; off >>= 1) v += __shfl_down(v, off, 64);
    if (lane == 0) smem[wid] = v;
    __syncthreads();
    if (ci == 0) {
        float S = smem[0] + smem[1] + smem[2] + smem[3];
        float sn2 = (float)(B_ * CIN) / ssum[0];
        float wn = wn_scale[co];
        coef_s = wn * sqrtf(sn2) * rsqrtf(wn * wn * sn2 * S + EPS);
    }
    __syncthreads();
    const float sc = sv * coef_s;
    const float* wp = w + ((size_t)co * CIN + ci) * 9;
    float wv[9];
#pragma unroll
    for (int tp = 0; tp < 9; ++tp) wv[tp] = wp[tp];
#pragma unroll
    for (int tap = 0; tap < 9; ++tap)
        wfull[(((size_t)b * 9 + tap) * COUT + co) * CIN + ci] = (__bf16)(wv[tap] * sc);
}

// ---------------- x fp32 NCHW -> bf16 [b][row][col 0..65][ci], via LDS transpose ----------------
// grid (64 rows, 16 b), 256 threads. Coalesced reads (256B runs), contiguous 2KB wave stores.
#define TP 260   // padded ci stride in LDS (520 B: odd dword stride -> conflict-free, 8B aligned)
__global__ __launch_bounds__(256) void xbf2_kernel(const float* __restrict__ x,
                                                   __bf16* __restrict__ xbf) {
    __shared__ __bf16 xs[64 * TP];
    const int row = blockIdx.x;
    const int b   = blockIdx.y;
    const int t   = threadIdx.x;
    const float* xbase = x + ((size_t)b * CIN * HW + row) * HW;   // + ci*4096 + col
#pragma unroll
    for (int k = 0; k < 16; ++k) {
        int idx = k * 256 + t;
        int ci = idx >> 4;
        int c4 = (idx & 15) * 4;
        float4 v = *(const float4*)(xbase + (size_t)ci * (HW * HW) + c4);
        xs[(c4 + 0) * TP + ci] = (__bf16)v.x;
        xs[(c4 + 1) * TP + ci] = (__bf16)v.y;
        xs[(c4 + 2) * TP + ci] = (__bf16)v.z;
        xs[(c4 + 3) * TP + ci] = (__bf16)v.w;
    }
    __syncthreads();
    ushort* orow = (ushort*)(xbf + (((size_t)b * HW + row) * 66) * CIN);
#pragma unroll
    for (int k = 0; k < 17; ++k) {
        int idx = k * 256 + t;
        if (idx < 66 * 64) {
            int col = idx >> 6;          // 0..65
            int ci4 = (idx & 63) * 4;
            ushort4 val = make_ushort4(0, 0, 0, 0);
            if (col != 0 && col != 65)
                val = *(const ushort4*)&xs[(col - 1) * TP + ci4];
            *(ushort4*)&orow[col * CIN + ci4] = val;
        }
    }
}

// ---------------- MFMA implicit-GEMM conv ----------------
// 1-D grid of 512 with XCD-affinity: b = bid%8 + 8*(bid>=256) -> each XCD's resident
// blocks touch only 2 batches (weights stay L2-hot). Block 512 = 8 waves:
// wy = wv>>1 (co quarter), wx = wv&1 (row in pair); 4x4 tiles of mfma 16x16x32.
__global__ __launch_bounds__(512, 4) void conv_mfma2(const __bf16* __restrict__ xbf,
                                                     const __bf16* __restrict__ zrow,
                                                     const __bf16* __restrict__ wfull,
                                                     float* __restrict__ out) {
    __shared__ __attribute__((aligned(16))) __bf16 xs[1088 * 8];  // 17408 B

    const int bid = blockIdx.x;
    const int b   = (bid & 7) + ((bid >= 256) ? 8 : 0);
    const int pxt = (bid >> 3) & 31;
    const int t = threadIdx.x;
    const int wv = t >> 6, lane = t & 63;
    const int wy = wv >> 1, wx = wv & 1;
    const int m16 = lane & 15, q = lane >> 4;
    const int r0 = pxt * 2;

    // staging sources: 17 wave-wide async16 over 1088 16B slots
    const __bf16* gsrc[3];
    unsigned ldsoff[3];
    int nst = 0;
#pragma unroll
    for (int i = 0; i < 3; ++i) {
        int instr = wv + 8 * i;
        if (instr < 17) {
            int slot = instr * 64 + lane;
            const __bf16* g;
            if (slot >= 1056) {
                g = zrow;
            } else {
                int qq  = slot / 264;
                int rem = slot - qq * 264;
                int row = rem / 66;
                int col = rem - row * 66;
                int gr = r0 - 1 + row;
                if ((unsigned)gr < 64u)
                    g = xbf + (((size_t)b * HW + gr) * 66 + col) * CIN + qq * 8;
                else
                    g = zrow + col * CIN + qq * 8;
            }
            gsrc[nst] = g;
            ldsoff[nst] = (unsigned)slot * 16;
            ++nst;
        }
    }

    f32x4 acc[4][4] = {};
    const __bf16* abase = wfull + (((size_t)b * 9 * COUT) + wy * 64 + m16) * CIN + q * 8;

    for (int ci0 = 0; ci0 < CIN; ci0 += 32) {
        for (int i = 0; i < nst; ++i)
            async16((char*)xs + ldsoff[i], gsrc[i] + ci0);
        __syncthreads();

        const __bf16* wb = abase + ci0;
#pragma unroll
        for (int tap = 0; tap < 9; ++tap) {
            const int dr = tap / 3, dc = tap % 3;
            bf16x8 af[4];
#pragma unroll
            for (int i = 0; i < 4; ++i)
                af[i] = *(const bf16x8*)(wb + (size_t)tap * (COUT * CIN) + i * 16 * CIN);
            bf16x8 bfr[4];
            const int rb = (((q * 4) + (wx + dr)) * 66 + (m16 + dc)) * 8;
#pragma unroll
            for (int j = 0; j < 4; ++j)
                bfr[j] = *(const bf16x8*)&xs[rb + j * 16 * 8];
#pragma unroll
            for (int i = 0; i < 4; ++i)
#pragma unroll
                for (int j = 0; j < 4; ++j)
                    acc[i][j] = __builtin_amdgcn_mfma_f32_16x16x32_bf16(af[i], bfr[j], acc[i][j], 0, 0, 0);
        }
        __syncthreads();
    }

    const int orow = r0 + wx;
#pragma unroll
    for (int i = 0; i < 4; ++i) {
        const int cobase = wy * 64 + i * 16 + q * 4;
#pragma unroll
        for (int reg = 0; reg < 4; ++reg) {
            float* op = out + ((size_t)b * COUT + (cobase + reg)) * (HW * HW) + orow * HW;
#pragma unroll
            for (int j = 0; j < 4; ++j)
                op[j * 16 + m16] = acc[i][j][reg];
        }
    }
}

extern "C" void kernel_launch(void* const* d_in, const int* in_sizes, int n_in,
                              void* d_out, int out_size, void* d_ws, size_t ws_size,
                              hipStream_t stream) {
    const float* x = (const float*)d_in[0];
    const float* s = (const float*)d_in[1];
    const float* w = (const float*)d_in[2];
    float* out = (float*)d_out;

    float* ws = (float*)d_ws;
    float*  ssum     = ws;
    float*  wn_scale = ws + 16;
    float*  wsq      = ws + 512;
    __bf16* wfull    = (__bf16*)(ws + 70656);            // 18,874,368 B
    __bf16* zrow     = (__bf16*)(ws + 4789248);          // 33,792 B
    __bf16* xbf      = (__bf16*)(ws + 4797696);          // 34,603,008 B

    hipMemsetAsync(zrow, 0, 33792, stream);
    stats_kernel<<<257, 256, 0, stream>>>(w, s, wsq, wn_scale, ssum);
    wmod_kernel<<<dim3(COUT, B_), 256, 0, stream>>>(w, s, wsq, wn_scale, ssum, wfull);
    xbf2_kernel<<<dim3(64, B_), 256, 0, stream>>>(x, xbf);
    conv_mfma2<<<512, 512, 0, stream>>>(xbf, zrow, wfull, out);
}

// Round 5
// 291.941 us; speedup vs baseline: 13.4025x; 1.0009x over previous
//
#include <hip/hip_runtime.h>
#include <hip/hip_bf16.h>

#define EPS 1e-8f
#define B_  16
#define CIN 256
#define COUT 256
#define HW 64

typedef __bf16 bf16x8 __attribute__((ext_vector_type(8)));
typedef float  f32x4  __attribute__((ext_vector_type(4)));

__device__ __forceinline__ void async16(void* lds, const void* g) {
    __builtin_amdgcn_global_load_lds(
        (const __attribute__((address_space(1))) unsigned int*)g,
        (__attribute__((address_space(3))) unsigned int*)lds,
        16, 0, 0);
}

// ---------------- fused stats: blocks 0..255 = per-co wsq/wn_scale; block 256 = ssum ----------------
__global__ __launch_bounds__(256) void stats_kernel(const float* __restrict__ w,
                                                    const float* __restrict__ s,
                                                    float* __restrict__ wsq,
                                                    float* __restrict__ wn_scale,
                                                    float* __restrict__ ssum_out) {
    __shared__ float smem[4];
    const int t = threadIdx.x;
    const int lane = t & 63, wid = t >> 6;
    if (blockIdx.x == 256) {
        float v = 0.f;
        for (int i = t; i < B_ * CIN; i += 256) { float sv = s[i]; v += sv * sv; }
        for (int off = 32; off > 0; off >>= 1) v += __shfl_down(v, off, 64);
        if (lane == 0) smem[wid] = v;
        __syncthreads();
        if (t == 0) ssum_out[0] = smem[0] + smem[1] + smem[2] + smem[3];
        return;
    }
    const int co = blockIdx.x;
    const float* wp = w + ((size_t)co * CIN + t) * 9;
    float q = 0.f;
#pragma unroll
    for (int tp = 0; tp < 9; ++tp) { float wv = wp[tp]; q += wv * wv; }
    wsq[co * CIN + t] = q;
    float v = q;
    for (int off = 32; off > 0; off >>= 1) v += __shfl_down(v, off, 64);
    if (lane == 0) smem[wid] = v;
    __syncthreads();
    if (t == 0) wn_scale[co] = rsqrtf((smem[0] + smem[1] + smem[2] + smem[3]) / 2304.f);
}

// ---------------- fused coef + modulated-weight materialization ----------------
__global__ __launch_bounds__(256) void wmod_kernel(const float* __restrict__ w,
                                                   const float* __restrict__ s,
                                                   const float* __restrict__ wsq,
                                                   const float* __restrict__ wn_scale,
                                                   const float* __restrict__ ssum,
                                                   __bf16* __restrict__ wfull) {
    __shared__ float smem[4];
    __shared__ float coef_s;
    const int co = blockIdx.x;
    const int b  = blockIdx.y;
    const int ci = threadIdx.x;
    const int lane = ci & 63, wid = ci >> 6;
    const float sv = s[b * CIN + ci];
    float v = sv * sv * wsq[co * CIN + ci];
    for (int off = 32; off > 0; off >>= 1) v += __shfl_down(v, off, 64);
    if (lane == 0) smem[wid] = v;
    __syncthreads();
    if (ci == 0) {
        float S = smem[0] + smem[1] + smem[2] + smem[3];
        float sn2 = (float)(B_ * CIN) / ssum[0];
        float wn = wn_scale[co];
        coef_s = wn * sqrtf(sn2) * rsqrtf(wn * wn * sn2 * S + EPS);
    }
    __syncthreads();
    const float sc = sv * coef_s;
    const float* wp = w + ((size_t)co * CIN + ci) * 9;
    float wv[9];
#pragma unroll
    for (int tp = 0; tp < 9; ++tp) wv[tp] = wp[tp];
#pragma unroll
    for (int tap = 0; tap < 9; ++tap)
        wfull[(((size_t)b * 9 + tap) * COUT + co) * CIN + ci] = (__bf16)(wv[tap] * sc);
}

// ---------------- x fp32 NCHW -> bf16 [b][row][col 0..65][ci], via LDS transpose ----------------
// TP=258 elements = 129 dwords: write lane row-stride 4*129 dw == 4 mod 32 -> 2-way (free).
#define TP 258
__global__ __launch_bounds__(256) void xbf2_kernel(const float* __restrict__ x,
                                                   __bf16* __restrict__ xbf) {
    __shared__ __bf16 xs[64 * TP];
    const int row = blockIdx.x;
    const int b   = blockIdx.y;
    const int t   = threadIdx.x;
    const float* xbase = x + ((size_t)b * CIN * HW + row) * HW;
#pragma unroll
    for (int k = 0; k < 16; ++k) {
        int idx = k * 256 + t;
        int ci = idx >> 4;
        int c4 = (idx & 15) * 4;
        float4 v = *(const float4*)(xbase + (size_t)ci * (HW * HW) + c4);
        xs[(c4 + 0) * TP + ci] = (__bf16)v.x;
        xs[(c4 + 1) * TP + ci] = (__bf16)v.y;
        xs[(c4 + 2) * TP + ci] = (__bf16)v.z;
        xs[(c4 + 3) * TP + ci] = (__bf16)v.w;
    }
    __syncthreads();
    uint* orow = (uint*)(xbf + (((size_t)b * HW + row) * 66) * CIN);
#pragma unroll
    for (int k = 0; k < 17; ++k) {
        int idx = k * 256 + t;
        if (idx < 66 * 64) {
            int col = idx >> 6;          // 0..65
            int ci4 = (idx & 63) * 4;
            uint u0 = 0, u1 = 0;
            if (col != 0 && col != 65) {
                u0 = *(const uint*)&xs[(col - 1) * TP + ci4];
                u1 = *(const uint*)&xs[(col - 1) * TP + ci4 + 2];
            }
            orow[(col * CIN + ci4) >> 1] = u0;
            orow[((col * CIN + ci4) >> 1) + 1] = u1;
        }
    }
}

// ---------------- MFMA implicit-GEMM conv, v3 ----------------
// grid 1024 (XCD-affine: b = bid%8 + 8*(bid>=512), row = (bid>>3)&63), block 256 = 4 waves.
// wave wy = co quarter (64 co); each wave computes one output row (64 px) via 4x4 MFMA tiles.
// Software-pipelined A-frag loads (tap+1 prefetch) + double-buffered async x staging.
// LDS x tile (per buf): 800 slots of 16B: slot = qq*200 + irow*66 + col (qq=ci octet, irow 0..2).
__global__ __launch_bounds__(256, 3) void conv_mfma3(const __bf16* __restrict__ xbf,
                                                     const __bf16* __restrict__ zrow,
                                                     const __bf16* __restrict__ wfull,
                                                     float* __restrict__ out) {
    __shared__ __attribute__((aligned(16))) __bf16 xs[2][800 * 8];   // 2 x 12800 B

    const int bid = blockIdx.x;
    const int b    = (bid & 7) + ((bid >= 512) ? 8 : 0);
    const int row0 = (bid >> 3) & 63;
    const int t = threadIdx.x;
    const int wy = t >> 6, lane = t & 63;
    const int m16 = lane & 15, q = lane >> 4;

    // staging sources: up to 4 async16 per thread over 800 slots (+224 dead lanes)
    const __bf16* gsrc[4];
    unsigned ldsoff[4];
    bool val[4];
#pragma unroll
    for (int i = 0; i < 4; ++i) {
        int slot = i * 256 + t;
        val[i] = slot < 800;
        int qq  = slot / 200;
        int rem = slot - qq * 200;
        int irow = rem / 66;
        int col  = rem - irow * 66;
        const __bf16* g;
        if (!val[i] || rem >= 198) {
            g = zrow;
        } else {
            int gr = row0 - 1 + irow;
            if ((unsigned)gr < 64u)
                g = xbf + (((size_t)b * HW + gr) * 66 + col) * CIN + qq * 8;
            else
                g = zrow + col * CIN + qq * 8;
        }
        gsrc[i] = g;
        ldsoff[i] = (unsigned)slot * 16;
    }

    // prologue: stage chunk 0 into buf 0
#pragma unroll
    for (int i = 0; i < 4; ++i)
        if (val[i]) async16((char*)xs[0] + ldsoff[i], gsrc[i]);

    f32x4 acc[4][4] = {};
    const __bf16* abase = wfull + (((size_t)b * 9 * COUT) + wy * 64 + m16) * CIN + q * 8;

    for (int cc = 0; cc < 8; ++cc) {
        const int ci0 = cc * 32;
        __syncthreads();                       // drains chunk-cc staging (issued one chunk ago)
        if (cc < 7) {
#pragma unroll
            for (int i = 0; i < 4; ++i)
                if (val[i]) async16((char*)xs[(cc + 1) & 1] + ldsoff[i], gsrc[i] + ci0 + 32);
        }
        const __bf16* wb = abase + ci0;
        const __bf16* xcur = xs[cc & 1];

        bf16x8 afc[4];
#pragma unroll
        for (int i = 0; i < 4; ++i)
            afc[i] = *(const bf16x8*)(wb + i * 16 * CIN);

#pragma unroll
        for (int tap = 0; tap < 9; ++tap) {
            bf16x8 afn[4];
            if (tap < 8) {
#pragma unroll
                for (int i = 0; i < 4; ++i)
                    afn[i] = *(const bf16x8*)(wb + (size_t)(tap + 1) * (COUT * CIN) + i * 16 * CIN);
            }
            const int dr = tap / 3, dc = tap % 3;
            bf16x8 bfr[4];
            const int rb = (q * 200 + dr * 66 + (m16 + dc)) * 8;
#pragma unroll
            for (int j = 0; j < 4; ++j)
                bfr[j] = *(const bf16x8*)&xcur[rb + j * 16 * 8];
#pragma unroll
            for (int i = 0; i < 4; ++i)
#pragma unroll
                for (int j = 0; j < 4; ++j)
                    acc[i][j] = __builtin_amdgcn_mfma_f32_16x16x32_bf16(afc[i], bfr[j], acc[i][j], 0, 0, 0);
            if (tap < 8) {
#pragma unroll
                for (int i = 0; i < 4; ++i) afc[i] = afn[i];
            }
        }
    }

    // epilogue: D col = lane&15 (pixel), row = q*4+reg (co)
#pragma unroll
    for (int i = 0; i < 4; ++i) {
        const int cobase = wy * 64 + i * 16 + q * 4;
#pragma unroll
        for (int reg = 0; reg < 4; ++reg) {
            float* op = out + ((size_t)b * COUT + (cobase + reg)) * (HW * HW) + row0 * HW;
#pragma unroll
            for (int j = 0; j < 4; ++j)
                op[j * 16 + m16] = acc[i][j][reg];
        }
    }
}

extern "C" void kernel_launch(void* const* d_in, const int* in_sizes, int n_in,
                              void* d_out, int out_size, void* d_ws, size_t ws_size,
                              hipStream_t stream) {
    const float* x = (const float*)d_in[0];
    const float* s = (const float*)d_in[1];
    const float* w = (const float*)d_in[2];
    float* out = (float*)d_out;

    float* ws = (float*)d_ws;
    float*  ssum     = ws;
    float*  wn_scale = ws + 16;
    float*  wsq      = ws + 512;
    __bf16* wfull    = (__bf16*)(ws + 70656);            // 18,874,368 B
    __bf16* zrow     = (__bf16*)(ws + 4789248);          // 33,792 B
    __bf16* xbf      = (__bf16*)(ws + 4797696);          // 34,603,008 B

    hipMemsetAsync(zrow, 0, 33792, stream);
    stats_kernel<<<257, 256, 0, stream>>>(w, s, wsq, wn_scale, ssum);
    wmod_kernel<<<dim3(COUT, B_), 256, 0, stream>>>(w, s, wsq, wn_scale, ssum, wfull);
    xbf2_kernel<<<dim3(64, B_), 256, 0, stream>>>(x, xbf);
    conv_mfma3<<<1024, 256, 0, stream>>>(xbf, zrow, wfull, out);
}